// Round 2
// baseline (814.260 us; speedup 1.0000x reference)
//
#include <hip/hip_runtime.h>

#define N_NODES 100000
#define N_EDGES 3200000
#define SCAN_BLK 1024
#define N_SCAN_BLKS ((N_NODES + SCAN_BLK - 1) / SCAN_BLK)   // 98

// ---------------- dense parts ----------------

// W12 = W1 @ W2  (32x64 @ 64x128 -> 32x128)
__global__ void gemm_w12_kernel(const float* __restrict__ W1,
                                const float* __restrict__ W2,
                                float* __restrict__ W12) {
    int idx = blockIdx.x * blockDim.x + threadIdx.x;
    if (idx >= 32 * 128) return;
    int r = idx >> 7;
    int c = idx & 127;
    float acc = 0.f;
#pragma unroll
    for (int k = 0; k < 64; ++k) acc += W1[r * 64 + k] * W2[k * 128 + c];
    W12[idx] = acc;
}

// out[i][j] = sum_k g2[i][k] * W12[k][j]   ([100000,32] @ [32,128])
__global__ void gemm_out_kernel(const float* __restrict__ g2,
                                const float* __restrict__ W12,
                                float* __restrict__ out) {
    __shared__ float w[32 * 128];
    for (int t = threadIdx.x; t < 32 * 128; t += blockDim.x) w[t] = W12[t];
    __syncthreads();
    int id = blockIdx.x * blockDim.x + threadIdx.x;
    int i = id >> 7;
    int j = id & 127;
    const float* g = g2 + i * 32;
    float acc = 0.f;
#pragma unroll
    for (int k = 0; k < 32; ++k) acc += g[k] * w[k * 128 + j];
    out[id] = acc;
}

// ---------------- CSR build ----------------

__global__ void hist_kernel(const int* __restrict__ row, int* __restrict__ counts) {
    int e = blockIdx.x * blockDim.x + threadIdx.x;
    if (e < N_EDGES) atomicAdd(&counts[row[e]], 1);
}

// per-block exclusive scan; writes within-block exclusive prefix + block total
__global__ void scan1_kernel(const int* __restrict__ counts,
                             int* __restrict__ pre, int* __restrict__ blk) {
    __shared__ int s[SCAN_BLK];
    int t = threadIdx.x;
    int i = blockIdx.x * SCAN_BLK + t;
    int v = (i < N_NODES) ? counts[i] : 0;
    s[t] = v;
    __syncthreads();
    for (int off = 1; off < SCAN_BLK; off <<= 1) {
        int add = (t >= off) ? s[t - off] : 0;
        __syncthreads();
        s[t] += add;
        __syncthreads();
    }
    int inc = s[t];
    if (i < N_NODES) pre[i] = inc - v;          // exclusive within block
    if (t == SCAN_BLK - 1) blk[blockIdx.x] = inc; // block total
}

// sequential scan of the 98 block totals (tiny)
__global__ void scan2_kernel(int* __restrict__ blk) {
    if (threadIdx.x == 0 && blockIdx.x == 0) {
        int run = 0;
        for (int b = 0; b < N_SCAN_BLKS; ++b) {
            int v = blk[b];
            blk[b] = run;
            run += v;
        }
    }
}

__global__ void addoff_kernel(const int* __restrict__ pre, const int* __restrict__ blk,
                              int* __restrict__ rs, int* __restrict__ cur) {
    int i = blockIdx.x * blockDim.x + threadIdx.x;
    if (i < N_NODES) {
        int v = pre[i] + blk[i >> 10];
        rs[i] = v;
        cur[i] = v;
    }
    if (i == 0) rs[N_NODES] = N_EDGES;
}

__global__ void scatter_kernel(const int* __restrict__ row, const int* __restrict__ col,
                               const float* __restrict__ val,
                               int* __restrict__ cur, int2* __restrict__ ep) {
    int e = blockIdx.x * blockDim.x + threadIdx.x;
    if (e >= N_EDGES) return;
    int r = row[e];
    int pos = atomicAdd(&cur[r], 1);
    ep[pos] = make_int2(col[e], __float_as_int(val[e]));
}

// ---------------- CSR SpMM ----------------
// one 64-lane wave per row; lanes 0..31 = feature j, two edges in flight
__global__ void spmm_csr_kernel(const int* __restrict__ rs,
                                const int2* __restrict__ ep,
                                const float* __restrict__ x,
                                float* __restrict__ out) {
    int gid = blockIdx.x * blockDim.x + threadIdx.x;
    int r = gid >> 6;
    if (r >= N_NODES) return;
    int lane = threadIdx.x & 63;
    int j = lane & 31;
    int half = lane >> 5;
    int s = rs[r], e = rs[r + 1];
    float acc = 0.f;
    for (int p = s + half; p < e; p += 2) {
        int2 cv = ep[p];
        acc += __int_as_float(cv.y) * x[cv.x * 32 + j];
    }
    acc += __shfl_xor(acc, 32, 64);
    if (half == 0) out[r * 32 + j] = acc;
}

// ---------------- fallback atomic SpMM (only if ws too small) ----------------
__global__ void spmm32_atomic_kernel(const int* __restrict__ row,
                                     const int* __restrict__ col,
                                     const float* __restrict__ val,
                                     const float* __restrict__ x,
                                     float* __restrict__ out) {
    int id = blockIdx.x * blockDim.x + threadIdx.x;
    int e = id >> 5;
    int j = id & 31;
    if (e >= N_EDGES) return;
    atomicAdd(&out[row[e] * 32 + j], val[e] * x[col[e] * 32 + j]);
}

extern "C" void kernel_launch(void* const* d_in, const int* in_sizes, int n_in,
                              void* d_out, int out_size, void* d_ws, size_t ws_size,
                              hipStream_t stream) {
    const float* feat = (const float*)d_in[0];   // [N, 32]
    const float* W1   = (const float*)d_in[1];   // [32, 64]
    const float* W2   = (const float*)d_in[2];   // [64, 128]
    const int*   erow = (const int*)d_in[3];     // [E]
    const int*   ecol = (const int*)d_in[4];     // [E]
    const float* eval_= (const float*)d_in[5];   // [E]
    float* out = (float*)d_out;                  // [N, 128]

    // workspace layout (floats/ints)
    float* W12    = (float*)d_ws;                       // 4096
    float* g1     = W12 + 4096;                         // N*32
    float* g2     = g1 + (size_t)N_NODES * 32;          // N*32
    int2*  ep     = (int2*)(g2 + (size_t)N_NODES * 32); // E int2 (8B-aligned)
    int*   counts = (int*)(ep + N_EDGES);               // N
    int*   pre    = counts + N_NODES;                   // N
    int*   blk    = pre + N_NODES;                      // 128
    int*   rs     = blk + 128;                          // N+1 (pad to N+2)
    int*   cur    = rs + N_NODES + 2;                   // N
    size_t needed = (size_t)((cur + N_NODES) - (int*)d_ws) * sizeof(int);

    gemm_w12_kernel<<<16, 256, 0, stream>>>(W1, W2, W12);

    if (ws_size >= needed) {
        // ---- build CSR once ----
        hipMemsetAsync(counts, 0, N_NODES * sizeof(int), stream);
        hist_kernel<<<(N_EDGES + 255) / 256, 256, 0, stream>>>(erow, counts);
        scan1_kernel<<<N_SCAN_BLKS, SCAN_BLK, 0, stream>>>(counts, pre, blk);
        scan2_kernel<<<1, 64, 0, stream>>>(blk);
        addoff_kernel<<<(N_NODES + 255) / 256, 256, 0, stream>>>(pre, blk, rs, cur);
        scatter_kernel<<<(N_EDGES + 255) / 256, 256, 0, stream>>>(erow, ecol, eval_, cur, ep);

        // ---- two CSR SpMMs (no zeroing needed: every row written) ----
        spmm_csr_kernel<<<(N_NODES * 64) / 256 + 1, 256, 0, stream>>>(rs, ep, feat, g1);
        spmm_csr_kernel<<<(N_NODES * 64) / 256 + 1, 256, 0, stream>>>(rs, ep, g1, g2);
    } else {
        // fallback: atomic path
        hipMemsetAsync(g1, 0, (size_t)N_NODES * 32 * 2 * sizeof(float), stream);
        spmm32_atomic_kernel<<<(N_EDGES * 32) / 256, 256, 0, stream>>>(erow, ecol, eval_, feat, g1);
        spmm32_atomic_kernel<<<(N_EDGES * 32) / 256, 256, 0, stream>>>(erow, ecol, eval_, g1, g2);
    }

    gemm_out_kernel<<<(N_NODES * 128) / 256, 256, 0, stream>>>(g2, W12, out);
}

// Round 4
// 694.153 us; speedup vs baseline: 1.1730x; 1.1730x over previous
//
#include <hip/hip_runtime.h>

#define N_NODES 100000
#define N_EDGES 3200000
#define RPB 128
#define NB ((N_NODES + RPB - 1) / RPB)       // 782
#define SCAN_BLK 1024
#define N_SCAN_BLKS ((N_NODES + SCAN_BLK - 1) / SCAN_BLK)   // 98

// ---------------- dense parts ----------------

__global__ void gemm_w12_kernel(const float* __restrict__ W1,
                                const float* __restrict__ W2,
                                float* __restrict__ W12) {
    int idx = blockIdx.x * blockDim.x + threadIdx.x;
    if (idx >= 32 * 128) return;
    int r = idx >> 7;
    int c = idx & 127;
    float acc = 0.f;
#pragma unroll
    for (int k = 0; k < 64; ++k) acc += W1[r * 64 + k] * W2[k * 128 + c];
    W12[idx] = acc;
}

__global__ void gemm_out_kernel(const float* __restrict__ g2,
                                const float* __restrict__ W12,
                                float* __restrict__ out) {
    __shared__ float w[32 * 128];
    for (int t = threadIdx.x; t < 32 * 128; t += blockDim.x) w[t] = W12[t];
    __syncthreads();
    int id = blockIdx.x * blockDim.x + threadIdx.x;
    int i = id >> 7;
    int j = id & 127;
    const float* g = g2 + i * 32;
    float acc = 0.f;
#pragma unroll
    for (int k = 0; k < 32; ++k) acc += g[k] * w[k * 128 + j];
    out[id] = acc;
}

// ---------------- per-row CSR offsets (R2-proven) ----------------

__global__ void hist_row_kernel(const int* __restrict__ row, int* __restrict__ counts) {
    int e = blockIdx.x * blockDim.x + threadIdx.x;
    if (e < N_EDGES) atomicAdd(&counts[row[e]], 1);
}

__global__ void scan1_kernel(const int* __restrict__ counts,
                             int* __restrict__ pre, int* __restrict__ blk) {
    __shared__ int s[SCAN_BLK];
    int t = threadIdx.x;
    int i = blockIdx.x * SCAN_BLK + t;
    int v = (i < N_NODES) ? counts[i] : 0;
    s[t] = v;
    __syncthreads();
    for (int off = 1; off < SCAN_BLK; off <<= 1) {
        int add = (t >= off) ? s[t - off] : 0;
        __syncthreads();
        s[t] += add;
        __syncthreads();
    }
    int inc = s[t];
    if (i < N_NODES) pre[i] = inc - v;
    if (t == SCAN_BLK - 1) blk[blockIdx.x] = inc;
}

__global__ void scan2_kernel(int* __restrict__ blk) {
    if (threadIdx.x == 0 && blockIdx.x == 0) {
        int run = 0;
        for (int b = 0; b < N_SCAN_BLKS; ++b) {
            int v = blk[b];
            blk[b] = run;
            run += v;
        }
    }
}

__global__ void addoff_kernel(const int* __restrict__ pre, const int* __restrict__ blk,
                              int* __restrict__ rs, int* __restrict__ cur_row,
                              int* __restrict__ cur_b) {
    int i = blockIdx.x * blockDim.x + threadIdx.x;
    if (i < N_NODES) {
        int v = pre[i] + blk[i >> 10];
        rs[i] = v;
        cur_row[i] = v;
        if ((i & 127) == 0) cur_b[i >> 7] = v;   // bucket start = rs[128*b]
    }
    if (i == 0) rs[N_NODES] = N_EDGES;
}

// ---------------- hop-1: block-aggregated BUCKET scatter ----------------
// packed = (col<<7) | (row & 127); writes bucket-contiguous runs into ebuf
__global__ void scatter_bucket_kernel(const int* __restrict__ row, const int* __restrict__ col,
                                      const float* __restrict__ val,
                                      int* __restrict__ cur_b, int2* __restrict__ ebuf) {
    __shared__ int h[NB];
    __shared__ int base[NB];
    for (int t = threadIdx.x; t < NB; t += blockDim.x) h[t] = 0;
    __syncthreads();
    int per = (N_EDGES + gridDim.x - 1) / gridDim.x;
    int s = blockIdx.x * per;
    int e = min(s + per, N_EDGES);
    for (int i = s + threadIdx.x; i < e; i += blockDim.x)
        atomicAdd(&h[row[i] >> 7], 1);
    __syncthreads();
    for (int t = threadIdx.x; t < NB; t += blockDim.x) {
        int c = h[t];
        base[t] = c ? atomicAdd(&cur_b[t], c) : 0;
        h[t] = 0;
    }
    __syncthreads();
    for (int i = s + threadIdx.x; i < e; i += blockDim.x) {
        int r = row[i];
        int b = r >> 7;
        int lp = atomicAdd(&h[b], 1);
        ebuf[base[b] + lp] = make_int2((col[i] << 7) | (r & 127), __float_as_int(val[i]));
    }
}

// ---------------- hop-2: within-bucket row placement ----------------
// reads bucket-contiguous ebuf; writes row-exact positions (32KB window per bucket)
__global__ void rowsort_kernel(const int* __restrict__ rs, const int2* __restrict__ ebuf,
                               int* __restrict__ cur_row, int2* __restrict__ ep) {
    int b = blockIdx.x;
    int lo = b * RPB;
    int hi = lo + RPB;
    int s = rs[lo];
    int e = (hi >= N_NODES) ? N_EDGES : rs[hi];
    for (int i = s + threadIdx.x; i < e; i += blockDim.x) {
        int2 cv = ebuf[i];
        int r = lo + (cv.x & 127);
        int pos = atomicAdd(&cur_row[r], 1);
        ep[pos] = make_int2(cv.x >> 7, cv.y);   // {col, valbits}
    }
}

// ---------------- CSR SpMM (R2-proven verbatim) ----------------
__global__ void spmm_csr_kernel(const int* __restrict__ rs,
                                const int2* __restrict__ ep,
                                const float* __restrict__ x,
                                float* __restrict__ out) {
    int gid = blockIdx.x * blockDim.x + threadIdx.x;
    int r = gid >> 6;
    if (r >= N_NODES) return;
    int lane = threadIdx.x & 63;
    int j = lane & 31;
    int half = lane >> 5;
    int s = rs[r], e = rs[r + 1];
    float acc = 0.f;
    for (int p = s + half; p < e; p += 2) {
        int2 cv = ep[p];
        acc += __int_as_float(cv.y) * x[cv.x * 32 + j];
    }
    acc += __shfl_xor(acc, 32, 64);
    if (half == 0) out[r * 32 + j] = acc;
}

// ---------------- fallback atomic SpMM ----------------
__global__ void spmm32_atomic_kernel(const int* __restrict__ row,
                                     const int* __restrict__ col,
                                     const float* __restrict__ val,
                                     const float* __restrict__ x,
                                     float* __restrict__ out) {
    int id = blockIdx.x * blockDim.x + threadIdx.x;
    int e = id >> 5;
    int j = id & 31;
    if (e >= N_EDGES) return;
    atomicAdd(&out[row[e] * 32 + j], val[e] * x[col[e] * 32 + j]);
}

extern "C" void kernel_launch(void* const* d_in, const int* in_sizes, int n_in,
                              void* d_out, int out_size, void* d_ws, size_t ws_size,
                              hipStream_t stream) {
    const float* feat = (const float*)d_in[0];   // [N, 32]
    const float* W1   = (const float*)d_in[1];   // [32, 64]
    const float* W2   = (const float*)d_in[2];   // [64, 128]
    const int*   erow = (const int*)d_in[3];     // [E]
    const int*   ecol = (const int*)d_in[4];     // [E]
    const float* eval_= (const float*)d_in[5];   // [E]
    float* out = (float*)d_out;                  // [N, 128]

    // ws: W12[4096] | g1[N*32] | g2[N*32] | ep[E int2] | counts[N] | pre[N] |
    //     blk[128] | rs[N+2] | cur_row[N] | cur_b[NB]
    float* W12     = (float*)d_ws;
    float* g1      = W12 + 4096;
    float* g2      = g1 + (size_t)N_NODES * 32;
    int2*  ep      = (int2*)(g2 + (size_t)N_NODES * 32);
    int*   counts  = (int*)(ep + N_EDGES);
    int*   pre     = counts + N_NODES;
    int*   blk     = pre + N_NODES;
    int*   rs      = blk + 128;
    int*   cur_row = rs + N_NODES + 2;
    int*   cur_b   = cur_row + N_NODES;
    size_t needed  = (size_t)((cur_b + NB) - (int*)d_ws) * sizeof(int);

    // bucket-grouped intermediate lives in d_out (25.6MB <= 51.2MB), fully
    // consumed by rowsort before gemm_out overwrites d_out.
    int2* ebuf = (int2*)d_out;

    gemm_w12_kernel<<<16, 256, 0, stream>>>(W1, W2, W12);

    if (ws_size >= needed) {
        hipMemsetAsync(counts, 0, N_NODES * sizeof(int), stream);
        hist_row_kernel<<<(N_EDGES + 255) / 256, 256, 0, stream>>>(erow, counts);
        scan1_kernel<<<N_SCAN_BLKS, SCAN_BLK, 0, stream>>>(counts, pre, blk);
        scan2_kernel<<<1, 64, 0, stream>>>(blk);
        addoff_kernel<<<(N_NODES + 255) / 256, 256, 0, stream>>>(pre, blk, rs, cur_row, cur_b);

        scatter_bucket_kernel<<<256, 256, 0, stream>>>(erow, ecol, eval_, cur_b, ebuf);
        rowsort_kernel<<<NB, 256, 0, stream>>>(rs, ebuf, cur_row, ep);

        spmm_csr_kernel<<<(N_NODES * 64) / 256, 256, 0, stream>>>(rs, ep, feat, g1);
        spmm_csr_kernel<<<(N_NODES * 64) / 256, 256, 0, stream>>>(rs, ep, g1, g2);
    } else {
        hipMemsetAsync(g1, 0, (size_t)N_NODES * 32 * 2 * sizeof(float), stream);
        spmm32_atomic_kernel<<<(N_EDGES * 32) / 256, 256, 0, stream>>>(erow, ecol, eval_, feat, g1);
        spmm32_atomic_kernel<<<(N_EDGES * 32) / 256, 256, 0, stream>>>(erow, ecol, eval_, g1, g2);
    }

    gemm_out_kernel<<<(N_NODES * 128) / 256, 256, 0, stream>>>(g2, W12, out);
}

// Round 5
// 386.529 us; speedup vs baseline: 2.1066x; 1.7959x over previous
//
#include <hip/hip_runtime.h>

#define N_NODES 100000
#define N_EDGES 3200000
#define RPB 128
#define NB ((N_NODES + RPB - 1) / RPB)       // 782 buckets

// ---------------- dense parts ----------------

__global__ void gemm_w12_kernel(const float* __restrict__ W1,
                                const float* __restrict__ W2,
                                float* __restrict__ W12) {
    int idx = blockIdx.x * blockDim.x + threadIdx.x;
    if (idx >= 32 * 128) return;
    int r = idx >> 7;
    int c = idx & 127;
    float acc = 0.f;
#pragma unroll
    for (int k = 0; k < 64; ++k) acc += W1[r * 64 + k] * W2[k * 128 + c];
    W12[idx] = acc;
}

__global__ void gemm_out_kernel(const float* __restrict__ g2,
                                const float* __restrict__ W12,
                                float* __restrict__ out) {
    __shared__ float w[32 * 128];
    for (int t = threadIdx.x; t < 32 * 128; t += blockDim.x) w[t] = W12[t];
    __syncthreads();
    int id = blockIdx.x * blockDim.x + threadIdx.x;
    int i = id >> 7;
    int j = id & 127;
    const float* g = g2 + i * 32;
    float acc = 0.f;
#pragma unroll
    for (int k = 0; k < 32; ++k) acc += g[k] * w[k * 128 + j];
    out[id] = acc;
}

// ---------------- bucket-level hist + scan ----------------

__global__ void hist_bucket_kernel(const int* __restrict__ row, int* __restrict__ cnt) {
    __shared__ int h[NB];
    for (int t = threadIdx.x; t < NB; t += blockDim.x) h[t] = 0;
    __syncthreads();
    int per = (N_EDGES + gridDim.x - 1) / gridDim.x;
    int s = blockIdx.x * per;
    int e = min(s + per, N_EDGES);
    for (int i = s + threadIdx.x; i < e; i += blockDim.x)
        atomicAdd(&h[row[i] >> 7], 1);
    __syncthreads();
    for (int t = threadIdx.x; t < NB; t += blockDim.x)
        if (h[t]) atomicAdd(&cnt[t], h[t]);
}

__global__ void scan_bucket_kernel(const int* __restrict__ cnt,
                                   int* __restrict__ offs, int* __restrict__ cur_b) {
    __shared__ int s[1024];
    int t = threadIdx.x;
    int v = (t < NB) ? cnt[t] : 0;
    s[t] = v;
    __syncthreads();
    for (int off = 1; off < 1024; off <<= 1) {
        int add = (t >= off) ? s[t - off] : 0;
        __syncthreads();
        s[t] += add;
        __syncthreads();
    }
    if (t < NB) { int x = s[t] - v; offs[t] = x; cur_b[t] = x; }
    if (t == 0) offs[NB] = N_EDGES;
}

// ---------------- hop-1: block-aggregated bucket scatter (R4-proven) ----------------
// packed = (col<<7) | (row & 127)
__global__ void scatter_bucket_kernel(const int* __restrict__ row, const int* __restrict__ col,
                                      const float* __restrict__ val,
                                      int* __restrict__ cur_b, int2* __restrict__ ebuf) {
    __shared__ int h[NB];
    __shared__ int base[NB];
    for (int t = threadIdx.x; t < NB; t += blockDim.x) h[t] = 0;
    __syncthreads();
    int per = (N_EDGES + gridDim.x - 1) / gridDim.x;
    int s = blockIdx.x * per;
    int e = min(s + per, N_EDGES);
    for (int i = s + threadIdx.x; i < e; i += blockDim.x)
        atomicAdd(&h[row[i] >> 7], 1);
    __syncthreads();
    for (int t = threadIdx.x; t < NB; t += blockDim.x) {
        int c = h[t];
        base[t] = c ? atomicAdd(&cur_b[t], c) : 0;
        h[t] = 0;
    }
    __syncthreads();
    for (int i = s + threadIdx.x; i < e; i += blockDim.x) {
        int r = row[i];
        int b = r >> 7;
        int lp = atomicAdd(&h[b], 1);
        ebuf[base[b] + lp] = make_int2((col[i] << 7) | (r & 127), __float_as_int(val[i]));
    }
}

// ---------------- hop-2: per-bucket LDS rowsort; also writes per-row rs ----------------
__global__ void rowsort_kernel(const int* __restrict__ offs, const int2* __restrict__ ebuf,
                               int2* __restrict__ ep, int* __restrict__ rs) {
    __shared__ int h[RPB];
    __shared__ int loff[RPB];
    __shared__ int curl[RPB];
    int b = blockIdx.x;
    int s = offs[b], e = offs[b + 1];
    int t = threadIdx.x;
    if (t < RPB) h[t] = 0;
    __syncthreads();
    for (int i = s + t; i < e; i += blockDim.x)
        atomicAdd(&h[ebuf[i].x & 127], 1);
    __syncthreads();
    if (t < RPB) loff[t] = h[t];
    __syncthreads();
    for (int off = 1; off < RPB; off <<= 1) {
        int add = (t < RPB && t >= off) ? loff[t - off] : 0;
        __syncthreads();
        if (t < RPB) loff[t] += add;
        __syncthreads();
    }
    if (t < RPB) {
        int excl = loff[t] - h[t];      // exclusive within-bucket offset
        curl[t] = excl;
        int r = b * RPB + t;
        if (r < N_NODES) rs[r] = s + excl;
    }
    if (b == 0 && t == 0) rs[N_NODES] = N_EDGES;
    __syncthreads();
    for (int i = s + t; i < e; i += blockDim.x) {
        int2 cv = ebuf[i];
        int rl = cv.x & 127;
        int pos = s + atomicAdd(&curl[rl], 1);
        ep[pos] = make_int2(cv.x >> 7, cv.y);   // {col, valbits}
    }
}

// ---------------- CSR SpMM, 4-deep unrolled (8 gathers in flight / wave) ----------------
__global__ void spmm_csr_kernel(const int* __restrict__ rs,
                                const int2* __restrict__ ep,
                                const float* __restrict__ x,
                                float* __restrict__ out) {
    int gid = blockIdx.x * blockDim.x + threadIdx.x;
    int r = gid >> 6;
    if (r >= N_NODES) return;
    int lane = threadIdx.x & 63;
    int j = lane & 31;
    int half = lane >> 5;
    int s = rs[r], e = rs[r + 1];
    float a0 = 0.f, a1 = 0.f, a2 = 0.f, a3 = 0.f;
    int p = s + half;
    for (; p + 6 < e; p += 8) {
        int2 c0 = ep[p];
        int2 c1 = ep[p + 2];
        int2 c2 = ep[p + 4];
        int2 c3 = ep[p + 6];
        float x0 = x[c0.x * 32 + j];
        float x1 = x[c1.x * 32 + j];
        float x2 = x[c2.x * 32 + j];
        float x3 = x[c3.x * 32 + j];
        a0 += __int_as_float(c0.y) * x0;
        a1 += __int_as_float(c1.y) * x1;
        a2 += __int_as_float(c2.y) * x2;
        a3 += __int_as_float(c3.y) * x3;
    }
    for (; p < e; p += 2) {
        int2 cv = ep[p];
        a0 += __int_as_float(cv.y) * x[cv.x * 32 + j];
    }
    float acc = (a0 + a1) + (a2 + a3);
    acc += __shfl_xor(acc, 32, 64);
    if (half == 0) out[r * 32 + j] = acc;
}

// ---------------- fallback atomic SpMM ----------------
__global__ void spmm32_atomic_kernel(const int* __restrict__ row,
                                     const int* __restrict__ col,
                                     const float* __restrict__ val,
                                     const float* __restrict__ x,
                                     float* __restrict__ out) {
    int id = blockIdx.x * blockDim.x + threadIdx.x;
    int e = id >> 5;
    int j = id & 31;
    if (e >= N_EDGES) return;
    atomicAdd(&out[row[e] * 32 + j], val[e] * x[col[e] * 32 + j]);
}

extern "C" void kernel_launch(void* const* d_in, const int* in_sizes, int n_in,
                              void* d_out, int out_size, void* d_ws, size_t ws_size,
                              hipStream_t stream) {
    const float* feat = (const float*)d_in[0];   // [N, 32]
    const float* W1   = (const float*)d_in[1];   // [32, 64]
    const float* W2   = (const float*)d_in[2];   // [64, 128]
    const int*   erow = (const int*)d_in[3];     // [E]
    const int*   ecol = (const int*)d_in[4];     // [E]
    const float* eval_= (const float*)d_in[5];   // [E]
    float* out = (float*)d_out;                  // [N, 128]

    // ws: W12[4096] | g1[N*32] | g2[N*32] | ep[E int2] | cnt[NB] | offs[NB+1] |
    //     cur_b[NB] | rs[N+2]
    float* W12   = (float*)d_ws;
    float* g1    = W12 + 4096;
    float* g2    = g1 + (size_t)N_NODES * 32;
    int2*  ep    = (int2*)(g2 + (size_t)N_NODES * 32);
    int*   cnt   = (int*)(ep + N_EDGES);
    int*   offs  = cnt + NB;
    int*   cur_b = offs + NB + 1;
    int*   rs    = cur_b + NB;
    size_t needed = (size_t)((rs + N_NODES + 2) - (int*)d_ws) * sizeof(int);

    // bucket-grouped intermediate lives in d_out (25.6MB <= 51.2MB), fully
    // consumed by rowsort before gemm_out overwrites d_out.
    int2* ebuf = (int2*)d_out;

    gemm_w12_kernel<<<16, 256, 0, stream>>>(W1, W2, W12);

    if (ws_size >= needed) {
        hipMemsetAsync(cnt, 0, NB * sizeof(int), stream);
        hist_bucket_kernel<<<256, 256, 0, stream>>>(erow, cnt);
        scan_bucket_kernel<<<1, 1024, 0, stream>>>(cnt, offs, cur_b);
        scatter_bucket_kernel<<<256, 256, 0, stream>>>(erow, ecol, eval_, cur_b, ebuf);
        rowsort_kernel<<<NB, 256, 0, stream>>>(offs, ebuf, ep, rs);

        spmm_csr_kernel<<<(N_NODES * 64) / 256, 256, 0, stream>>>(rs, ep, feat, g1);
        spmm_csr_kernel<<<(N_NODES * 64) / 256, 256, 0, stream>>>(rs, ep, g1, g2);
    } else {
        hipMemsetAsync(g1, 0, (size_t)N_NODES * 32 * 2 * sizeof(float), stream);
        spmm32_atomic_kernel<<<(N_EDGES * 32) / 256, 256, 0, stream>>>(erow, ecol, eval_, feat, g1);
        spmm32_atomic_kernel<<<(N_EDGES * 32) / 256, 256, 0, stream>>>(erow, ecol, eval_, g1, g2);
    }

    gemm_out_kernel<<<(N_NODES * 128) / 256, 256, 0, stream>>>(g2, W12, out);
}

// Round 6
// 305.842 us; speedup vs baseline: 2.6624x; 1.2638x over previous
//
#include <hip/hip_runtime.h>

#define N_NODES 100000
#define N_EDGES 3200000
#define RPB 128
#define NB ((N_NODES + RPB - 1) / RPB)       // 782 buckets

// ---------------- dense parts ----------------

__global__ void gemm_w12_kernel(const float* __restrict__ W1,
                                const float* __restrict__ W2,
                                float* __restrict__ W12) {
    int idx = blockIdx.x * blockDim.x + threadIdx.x;
    if (idx >= 32 * 128) return;
    int r = idx >> 7;
    int c = idx & 127;
    float acc = 0.f;
#pragma unroll
    for (int k = 0; k < 64; ++k) acc += W1[r * 64 + k] * W2[k * 128 + c];
    W12[idx] = acc;
}

// out[r][jo:jo+4] = sum_k g2[r][k] * W12[k][jo:jo+4]
// W12 column-block in 32 float4 registers; g2 row via 8 coalesced float4 loads.
__global__ void gemm_out_kernel(const float* __restrict__ g2,
                                const float* __restrict__ W12,
                                float* __restrict__ out) {
    int tid = threadIdx.x;
    int jo = (tid & 31) * 4;     // column group: 32 groups x 4 cols = 128
    int rl = tid >> 5;           // 8 row lanes per block
    float4 w[32];
#pragma unroll
    for (int k = 0; k < 32; ++k) w[k] = *(const float4*)&W12[k * 128 + jo];
    for (int r = blockIdx.x * 8 + rl; r < N_NODES; r += gridDim.x * 8) {
        const float4* g4 = (const float4*)(g2 + (size_t)r * 32);
        float4 acc = make_float4(0.f, 0.f, 0.f, 0.f);
#pragma unroll
        for (int q = 0; q < 8; ++q) {
            float4 gv = g4[q];
            int k = q * 4;
            acc.x += gv.x * w[k].x;     acc.y += gv.x * w[k].y;
            acc.z += gv.x * w[k].z;     acc.w += gv.x * w[k].w;
            acc.x += gv.y * w[k + 1].x; acc.y += gv.y * w[k + 1].y;
            acc.z += gv.y * w[k + 1].z; acc.w += gv.y * w[k + 1].w;
            acc.x += gv.z * w[k + 2].x; acc.y += gv.z * w[k + 2].y;
            acc.z += gv.z * w[k + 2].z; acc.w += gv.z * w[k + 2].w;
            acc.x += gv.w * w[k + 3].x; acc.y += gv.w * w[k + 3].y;
            acc.z += gv.w * w[k + 3].z; acc.w += gv.w * w[k + 3].w;
        }
        *(float4*)&out[(size_t)r * 128 + jo] = acc;
    }
}

// ---------------- bucket-level hist + scan ----------------

__global__ void hist_bucket_kernel(const int* __restrict__ row, int* __restrict__ cnt) {
    __shared__ int h[NB];
    for (int t = threadIdx.x; t < NB; t += blockDim.x) h[t] = 0;
    __syncthreads();
    int per = (N_EDGES + gridDim.x - 1) / gridDim.x;
    int s = blockIdx.x * per;
    int e = min(s + per, N_EDGES);
    for (int i = s + threadIdx.x; i < e; i += blockDim.x)
        atomicAdd(&h[row[i] >> 7], 1);
    __syncthreads();
    for (int t = threadIdx.x; t < NB; t += blockDim.x)
        if (h[t]) atomicAdd(&cnt[t], h[t]);
}

__global__ void scan_bucket_kernel(const int* __restrict__ cnt,
                                   int* __restrict__ offs, int* __restrict__ cur_b) {
    __shared__ int s[1024];
    int t = threadIdx.x;
    int v = (t < NB) ? cnt[t] : 0;
    s[t] = v;
    __syncthreads();
    for (int off = 1; off < 1024; off <<= 1) {
        int add = (t >= off) ? s[t - off] : 0;
        __syncthreads();
        s[t] += add;
        __syncthreads();
    }
    if (t < NB) { int x = s[t] - v; offs[t] = x; cur_b[t] = x; }
    if (t == 0) offs[NB] = N_EDGES;
}

// ---------------- hop-1: block-aggregated bucket scatter ----------------
// packed = (col<<7) | (row & 127)
__global__ void scatter_bucket_kernel(const int* __restrict__ row, const int* __restrict__ col,
                                      const float* __restrict__ val,
                                      int* __restrict__ cur_b, int2* __restrict__ ebuf) {
    __shared__ int h[NB];
    __shared__ int base[NB];
    for (int t = threadIdx.x; t < NB; t += blockDim.x) h[t] = 0;
    __syncthreads();
    int per = (N_EDGES + gridDim.x - 1) / gridDim.x;
    int s = blockIdx.x * per;
    int e = min(s + per, N_EDGES);
    for (int i = s + threadIdx.x; i < e; i += blockDim.x)
        atomicAdd(&h[row[i] >> 7], 1);
    __syncthreads();
    for (int t = threadIdx.x; t < NB; t += blockDim.x) {
        int c = h[t];
        base[t] = c ? atomicAdd(&cur_b[t], c) : 0;
        h[t] = 0;
    }
    __syncthreads();
    for (int i = s + threadIdx.x; i < e; i += blockDim.x) {
        int r = row[i];
        int b = r >> 7;
        int lp = atomicAdd(&h[b], 1);
        ebuf[base[b] + lp] = make_int2((col[i] << 7) | (r & 127), __float_as_int(val[i]));
    }
}

// ---------------- hop-2: per-bucket LDS rowsort; also writes per-row rs ----------------
__global__ void rowsort_kernel(const int* __restrict__ offs, const int2* __restrict__ ebuf,
                               int2* __restrict__ ep, int* __restrict__ rs) {
    __shared__ int h[RPB];
    __shared__ int loff[RPB];
    __shared__ int curl[RPB];
    int b = blockIdx.x;
    int s = offs[b], e = offs[b + 1];
    int t = threadIdx.x;
    if (t < RPB) h[t] = 0;
    __syncthreads();
    for (int i = s + t; i < e; i += blockDim.x)
        atomicAdd(&h[ebuf[i].x & 127], 1);
    __syncthreads();
    if (t < RPB) loff[t] = h[t];
    __syncthreads();
    for (int off = 1; off < RPB; off <<= 1) {
        int add = (t < RPB && t >= off) ? loff[t - off] : 0;
        __syncthreads();
        if (t < RPB) loff[t] += add;
        __syncthreads();
    }
    if (t < RPB) {
        int excl = loff[t] - h[t];
        curl[t] = excl;
        int r = b * RPB + t;
        if (r < N_NODES) rs[r] = s + excl;
    }
    if (b == 0 && t == 0) rs[N_NODES] = N_EDGES;
    __syncthreads();
    for (int i = s + t; i < e; i += blockDim.x) {
        int2 cv = ebuf[i];
        int rl = cv.x & 127;
        int pos = s + atomicAdd(&curl[rl], 1);
        ep[pos] = make_int2(cv.x >> 7, cv.y);   // {col, valbits}
    }
}

// ---------------- CSR SpMM, 8-deep unrolled (16 gathers in flight / wave) ----------------
__global__ void spmm_csr_kernel(const int* __restrict__ rs,
                                const int2* __restrict__ ep,
                                const float* __restrict__ x,
                                float* __restrict__ out) {
    int gid = blockIdx.x * blockDim.x + threadIdx.x;
    int r = gid >> 6;
    if (r >= N_NODES) return;
    int lane = threadIdx.x & 63;
    int j = lane & 31;
    int half = lane >> 5;
    int s = rs[r], e = rs[r + 1];
    float a0 = 0.f, a1 = 0.f, a2 = 0.f, a3 = 0.f;
    int p = s + half;
    for (; p + 14 < e; p += 16) {
        int2 c0 = ep[p];
        int2 c1 = ep[p + 2];
        int2 c2 = ep[p + 4];
        int2 c3 = ep[p + 6];
        int2 c4 = ep[p + 8];
        int2 c5 = ep[p + 10];
        int2 c6 = ep[p + 12];
        int2 c7 = ep[p + 14];
        float x0 = x[c0.x * 32 + j];
        float x1 = x[c1.x * 32 + j];
        float x2 = x[c2.x * 32 + j];
        float x3 = x[c3.x * 32 + j];
        float x4 = x[c4.x * 32 + j];
        float x5 = x[c5.x * 32 + j];
        float x6 = x[c6.x * 32 + j];
        float x7 = x[c7.x * 32 + j];
        a0 += __int_as_float(c0.y) * x0;
        a1 += __int_as_float(c1.y) * x1;
        a2 += __int_as_float(c2.y) * x2;
        a3 += __int_as_float(c3.y) * x3;
        a0 += __int_as_float(c4.y) * x4;
        a1 += __int_as_float(c5.y) * x5;
        a2 += __int_as_float(c6.y) * x6;
        a3 += __int_as_float(c7.y) * x7;
    }
    for (; p + 6 < e; p += 8) {
        int2 c0 = ep[p];
        int2 c1 = ep[p + 2];
        int2 c2 = ep[p + 4];
        int2 c3 = ep[p + 6];
        float x0 = x[c0.x * 32 + j];
        float x1 = x[c1.x * 32 + j];
        float x2 = x[c2.x * 32 + j];
        float x3 = x[c3.x * 32 + j];
        a0 += __int_as_float(c0.y) * x0;
        a1 += __int_as_float(c1.y) * x1;
        a2 += __int_as_float(c2.y) * x2;
        a3 += __int_as_float(c3.y) * x3;
    }
    for (; p < e; p += 2) {
        int2 cv = ep[p];
        a0 += __int_as_float(cv.y) * x[cv.x * 32 + j];
    }
    float acc = (a0 + a1) + (a2 + a3);
    acc += __shfl_xor(acc, 32, 64);
    if (half == 0) out[r * 32 + j] = acc;
}

// ---------------- fallback atomic SpMM ----------------
__global__ void spmm32_atomic_kernel(const int* __restrict__ row,
                                     const int* __restrict__ col,
                                     const float* __restrict__ val,
                                     const float* __restrict__ x,
                                     float* __restrict__ out) {
    int id = blockIdx.x * blockDim.x + threadIdx.x;
    int e = id >> 5;
    int j = id & 31;
    if (e >= N_EDGES) return;
    atomicAdd(&out[row[e] * 32 + j], val[e] * x[col[e] * 32 + j]);
}

__global__ void gemm_out_fallback_kernel(const float* __restrict__ g2,
                                         const float* __restrict__ W12,
                                         float* __restrict__ out) {
    int id = blockIdx.x * blockDim.x + threadIdx.x;
    int i = id >> 7;
    int j = id & 127;
    const float* g = g2 + i * 32;
    float acc = 0.f;
#pragma unroll
    for (int k = 0; k < 32; ++k) acc += g[k] * W12[k * 128 + j];
    out[id] = acc;
}

extern "C" void kernel_launch(void* const* d_in, const int* in_sizes, int n_in,
                              void* d_out, int out_size, void* d_ws, size_t ws_size,
                              hipStream_t stream) {
    const float* feat = (const float*)d_in[0];   // [N, 32]
    const float* W1   = (const float*)d_in[1];   // [32, 64]
    const float* W2   = (const float*)d_in[2];   // [64, 128]
    const int*   erow = (const int*)d_in[3];     // [E]
    const int*   ecol = (const int*)d_in[4];     // [E]
    const float* eval_= (const float*)d_in[5];   // [E]
    float* out = (float*)d_out;                  // [N, 128]

    // ws: W12[4096] | g1[N*32] | g2[N*32] | ep[E int2] | cnt[NB] | offs[NB+1] |
    //     cur_b[NB] | rs[N+2]
    float* W12   = (float*)d_ws;
    float* g1    = W12 + 4096;
    float* g2    = g1 + (size_t)N_NODES * 32;
    int2*  ep    = (int2*)(g2 + (size_t)N_NODES * 32);
    int*   cnt   = (int*)(ep + N_EDGES);
    int*   offs  = cnt + NB;
    int*   cur_b = offs + NB + 1;
    int*   rs    = cur_b + NB;
    size_t needed = (size_t)((rs + N_NODES + 2) - (int*)d_ws) * sizeof(int);

    // bucket-grouped intermediate lives in d_out (25.6MB <= 51.2MB), fully
    // consumed by rowsort before gemm_out overwrites d_out.
    int2* ebuf = (int2*)d_out;

    gemm_w12_kernel<<<16, 256, 0, stream>>>(W1, W2, W12);

    if (ws_size >= needed) {
        hipMemsetAsync(cnt, 0, NB * sizeof(int), stream);
        hist_bucket_kernel<<<256, 256, 0, stream>>>(erow, cnt);
        scan_bucket_kernel<<<1, 1024, 0, stream>>>(cnt, offs, cur_b);
        scatter_bucket_kernel<<<256, 256, 0, stream>>>(erow, ecol, eval_, cur_b, ebuf);
        rowsort_kernel<<<NB, 256, 0, stream>>>(offs, ebuf, ep, rs);

        spmm_csr_kernel<<<(N_NODES * 64) / 256, 256, 0, stream>>>(rs, ep, feat, g1);
        spmm_csr_kernel<<<(N_NODES * 64) / 256, 256, 0, stream>>>(rs, ep, g1, g2);

        gemm_out_kernel<<<1024, 256, 0, stream>>>(g2, W12, out);
    } else {
        hipMemsetAsync(g1, 0, (size_t)N_NODES * 32 * 2 * sizeof(float), stream);
        spmm32_atomic_kernel<<<(N_EDGES * 32) / 256, 256, 0, stream>>>(erow, ecol, eval_, feat, g1);
        spmm32_atomic_kernel<<<(N_EDGES * 32) / 256, 256, 0, stream>>>(erow, ecol, eval_, g1, g2);
        gemm_out_fallback_kernel<<<(N_NODES * 128) / 256, 256, 0, stream>>>(g2, W12, out);
    }
}

// Round 7
// 280.210 us; speedup vs baseline: 2.9059x; 1.0915x over previous
//
#include <hip/hip_runtime.h>

#define N_NODES 100000
#define N_EDGES 3200000
#define RPB 128
#define NB ((N_NODES + RPB - 1) / RPB)       // 782 buckets

// ---------------- dense parts ----------------

__global__ void gemm_w12_kernel(const float* __restrict__ W1,
                                const float* __restrict__ W2,
                                float* __restrict__ W12) {
    int idx = blockIdx.x * blockDim.x + threadIdx.x;
    if (idx >= 32 * 128) return;
    int r = idx >> 7;
    int c = idx & 127;
    float acc = 0.f;
#pragma unroll
    for (int k = 0; k < 64; ++k) acc += W1[r * 64 + k] * W2[k * 128 + c];
    W12[idx] = acc;
}

// out[r][jo:jo+4] = sum_k g2[r][k] * W12[k][jo:jo+4]
__global__ void gemm_out_kernel(const float* __restrict__ g2,
                                const float* __restrict__ W12,
                                float* __restrict__ out) {
    int tid = threadIdx.x;
    int jo = (tid & 31) * 4;
    int rl = tid >> 5;
    float4 w[32];
#pragma unroll
    for (int k = 0; k < 32; ++k) w[k] = *(const float4*)&W12[k * 128 + jo];
    for (int r = blockIdx.x * 8 + rl; r < N_NODES; r += gridDim.x * 8) {
        const float4* g4 = (const float4*)(g2 + (size_t)r * 32);
        float4 acc = make_float4(0.f, 0.f, 0.f, 0.f);
#pragma unroll
        for (int q = 0; q < 8; ++q) {
            float4 gv = g4[q];
            int k = q * 4;
            acc.x += gv.x * w[k].x;     acc.y += gv.x * w[k].y;
            acc.z += gv.x * w[k].z;     acc.w += gv.x * w[k].w;
            acc.x += gv.y * w[k + 1].x; acc.y += gv.y * w[k + 1].y;
            acc.z += gv.y * w[k + 1].z; acc.w += gv.y * w[k + 1].w;
            acc.x += gv.z * w[k + 2].x; acc.y += gv.z * w[k + 2].y;
            acc.z += gv.z * w[k + 2].z; acc.w += gv.z * w[k + 2].w;
            acc.x += gv.w * w[k + 3].x; acc.y += gv.w * w[k + 3].y;
            acc.z += gv.w * w[k + 3].z; acc.w += gv.w * w[k + 3].w;
        }
        *(float4*)&out[(size_t)r * 128 + jo] = acc;
    }
}

// ---------------- bucket-level hist + scan ----------------

__global__ void hist_bucket_kernel(const int* __restrict__ row, int* __restrict__ cnt) {
    __shared__ int h[NB];
    for (int t = threadIdx.x; t < NB; t += blockDim.x) h[t] = 0;
    __syncthreads();
    int per = (N_EDGES + gridDim.x - 1) / gridDim.x;
    int s = blockIdx.x * per;
    int e = min(s + per, N_EDGES);
    for (int i = s + threadIdx.x; i < e; i += blockDim.x)
        atomicAdd(&h[row[i] >> 7], 1);
    __syncthreads();
    for (int t = threadIdx.x; t < NB; t += blockDim.x)
        if (h[t]) atomicAdd(&cnt[t], h[t]);
}

__global__ void scan_bucket_kernel(const int* __restrict__ cnt,
                                   int* __restrict__ offs, int* __restrict__ cur_b) {
    __shared__ int s[1024];
    int t = threadIdx.x;
    int v = (t < NB) ? cnt[t] : 0;
    s[t] = v;
    __syncthreads();
    for (int off = 1; off < 1024; off <<= 1) {
        int add = (t >= off) ? s[t - off] : 0;
        __syncthreads();
        s[t] += add;
        __syncthreads();
    }
    if (t < NB) { int x = s[t] - v; offs[t] = x; cur_b[t] = x; }
    if (t == 0) offs[NB] = N_EDGES;
}

// ---------------- hop-1: block-aggregated bucket scatter (1024 threads) ----------------
// packed = (col<<7) | (row & 127)
__global__ void scatter_bucket_kernel(const int* __restrict__ row, const int* __restrict__ col,
                                      const float* __restrict__ val,
                                      int* __restrict__ cur_b, int2* __restrict__ ebuf) {
    __shared__ int h[NB];
    __shared__ int base[NB];
    for (int t = threadIdx.x; t < NB; t += blockDim.x) h[t] = 0;
    __syncthreads();
    int per = (N_EDGES + gridDim.x - 1) / gridDim.x;
    int s = blockIdx.x * per;
    int e = min(s + per, N_EDGES);
    for (int i = s + threadIdx.x; i < e; i += blockDim.x)
        atomicAdd(&h[row[i] >> 7], 1);
    __syncthreads();
    for (int t = threadIdx.x; t < NB; t += blockDim.x) {
        int c = h[t];
        base[t] = c ? atomicAdd(&cur_b[t], c) : 0;
        h[t] = 0;
    }
    __syncthreads();
    for (int i = s + threadIdx.x; i < e; i += blockDim.x) {
        int r = row[i];
        int b = r >> 7;
        int lp = atomicAdd(&h[b], 1);
        ebuf[base[b] + lp] = make_int2((col[i] << 7) | (r & 127), __float_as_int(val[i]));
    }
}

// ---------------- hop-2: per-bucket LDS rowsort (512 threads); writes rs ----------------
__global__ void rowsort_kernel(const int* __restrict__ offs, const int2* __restrict__ ebuf,
                               int2* __restrict__ ep, int* __restrict__ rs) {
    __shared__ int h[RPB];
    __shared__ int loff[RPB];
    __shared__ int curl[RPB];
    int b = blockIdx.x;
    int s = offs[b], e = offs[b + 1];
    int t = threadIdx.x;
    if (t < RPB) h[t] = 0;
    __syncthreads();
    for (int i = s + t; i < e; i += blockDim.x)
        atomicAdd(&h[ebuf[i].x & 127], 1);
    __syncthreads();
    if (t < RPB) loff[t] = h[t];
    __syncthreads();
    for (int off = 1; off < RPB; off <<= 1) {
        int add = (t < RPB && t >= off) ? loff[t - off] : 0;
        __syncthreads();
        if (t < RPB) loff[t] += add;
        __syncthreads();
    }
    if (t < RPB) {
        int excl = loff[t] - h[t];
        curl[t] = excl;
        int r = b * RPB + t;
        if (r < N_NODES) rs[r] = s + excl;
    }
    if (b == 0 && t == 0) rs[N_NODES] = N_EDGES;
    __syncthreads();
    for (int i = s + t; i < e; i += blockDim.x) {
        int2 cv = ebuf[i];
        int rl = cv.x & 127;
        int pos = s + atomicAdd(&curl[rl], 1);
        ep[pos] = make_int2(cv.x >> 7, cv.y);   // {col, valbits}
    }
}

// ---------------- CSR SpMM, 8-deep unrolled ----------------
__global__ void spmm_csr_kernel(const int* __restrict__ rs,
                                const int2* __restrict__ ep,
                                const float* __restrict__ x,
                                float* __restrict__ out) {
    int gid = blockIdx.x * blockDim.x + threadIdx.x;
    int r = gid >> 6;
    if (r >= N_NODES) return;
    int lane = threadIdx.x & 63;
    int j = lane & 31;
    int half = lane >> 5;
    int s = rs[r], e = rs[r + 1];
    float a0 = 0.f, a1 = 0.f, a2 = 0.f, a3 = 0.f;
    int p = s + half;
    for (; p + 14 < e; p += 16) {
        int2 c0 = ep[p];
        int2 c1 = ep[p + 2];
        int2 c2 = ep[p + 4];
        int2 c3 = ep[p + 6];
        int2 c4 = ep[p + 8];
        int2 c5 = ep[p + 10];
        int2 c6 = ep[p + 12];
        int2 c7 = ep[p + 14];
        float x0 = x[c0.x * 32 + j];
        float x1 = x[c1.x * 32 + j];
        float x2 = x[c2.x * 32 + j];
        float x3 = x[c3.x * 32 + j];
        float x4 = x[c4.x * 32 + j];
        float x5 = x[c5.x * 32 + j];
        float x6 = x[c6.x * 32 + j];
        float x7 = x[c7.x * 32 + j];
        a0 += __int_as_float(c0.y) * x0;
        a1 += __int_as_float(c1.y) * x1;
        a2 += __int_as_float(c2.y) * x2;
        a3 += __int_as_float(c3.y) * x3;
        a0 += __int_as_float(c4.y) * x4;
        a1 += __int_as_float(c5.y) * x5;
        a2 += __int_as_float(c6.y) * x6;
        a3 += __int_as_float(c7.y) * x7;
    }
    for (; p + 6 < e; p += 8) {
        int2 c0 = ep[p];
        int2 c1 = ep[p + 2];
        int2 c2 = ep[p + 4];
        int2 c3 = ep[p + 6];
        float x0 = x[c0.x * 32 + j];
        float x1 = x[c1.x * 32 + j];
        float x2 = x[c2.x * 32 + j];
        float x3 = x[c3.x * 32 + j];
        a0 += __int_as_float(c0.y) * x0;
        a1 += __int_as_float(c1.y) * x1;
        a2 += __int_as_float(c2.y) * x2;
        a3 += __int_as_float(c3.y) * x3;
    }
    for (; p < e; p += 2) {
        int2 cv = ep[p];
        a0 += __int_as_float(cv.y) * x[cv.x * 32 + j];
    }
    float acc = (a0 + a1) + (a2 + a3);
    acc += __shfl_xor(acc, 32, 64);
    if (half == 0) out[r * 32 + j] = acc;
}

// ---------------- fallback path ----------------
__global__ void spmm32_atomic_kernel(const int* __restrict__ row,
                                     const int* __restrict__ col,
                                     const float* __restrict__ val,
                                     const float* __restrict__ x,
                                     float* __restrict__ out) {
    int id = blockIdx.x * blockDim.x + threadIdx.x;
    int e = id >> 5;
    int j = id & 31;
    if (e >= N_EDGES) return;
    atomicAdd(&out[row[e] * 32 + j], val[e] * x[col[e] * 32 + j]);
}

__global__ void gemm_out_fallback_kernel(const float* __restrict__ g2,
                                         const float* __restrict__ W12,
                                         float* __restrict__ out) {
    int id = blockIdx.x * blockDim.x + threadIdx.x;
    int i = id >> 7;
    int j = id & 127;
    const float* g = g2 + i * 32;
    float acc = 0.f;
#pragma unroll
    for (int k = 0; k < 32; ++k) acc += g[k] * W12[k * 128 + j];
    out[id] = acc;
}

extern "C" void kernel_launch(void* const* d_in, const int* in_sizes, int n_in,
                              void* d_out, int out_size, void* d_ws, size_t ws_size,
                              hipStream_t stream) {
    const float* feat = (const float*)d_in[0];   // [N, 32]
    const float* W1   = (const float*)d_in[1];   // [32, 64]
    const float* W2   = (const float*)d_in[2];   // [64, 128]
    const int*   erow = (const int*)d_in[3];     // [E]
    const int*   ecol = (const int*)d_in[4];     // [E]
    const float* eval_= (const float*)d_in[5];   // [E]
    float* out = (float*)d_out;                  // [N, 128]

    // ws: W12[4096] | g1[N*32] | g2[N*32] | ep[E int2] | cnt[NB] | offs[NB+1] |
    //     cur_b[NB] | rs[N+2]
    float* W12   = (float*)d_ws;
    float* g1    = W12 + 4096;
    float* g2    = g1 + (size_t)N_NODES * 32;
    int2*  ep    = (int2*)(g2 + (size_t)N_NODES * 32);
    int*   cnt   = (int*)(ep + N_EDGES);
    int*   offs  = cnt + NB;
    int*   cur_b = offs + NB + 1;
    int*   rs    = cur_b + NB;
    size_t needed = (size_t)((rs + N_NODES + 2) - (int*)d_ws) * sizeof(int);

    // bucket-grouped intermediate lives in d_out (25.6MB <= 51.2MB), fully
    // consumed by rowsort before gemm_out overwrites d_out.
    int2* ebuf = (int2*)d_out;

    gemm_w12_kernel<<<16, 256, 0, stream>>>(W1, W2, W12);

    if (ws_size >= needed) {
        hipMemsetAsync(cnt, 0, NB * sizeof(int), stream);
        hist_bucket_kernel<<<256, 1024, 0, stream>>>(erow, cnt);
        scan_bucket_kernel<<<1, 1024, 0, stream>>>(cnt, offs, cur_b);
        scatter_bucket_kernel<<<256, 1024, 0, stream>>>(erow, ecol, eval_, cur_b, ebuf);
        rowsort_kernel<<<NB, 512, 0, stream>>>(offs, ebuf, ep, rs);

        spmm_csr_kernel<<<(N_NODES * 64) / 256, 256, 0, stream>>>(rs, ep, feat, g1);
        spmm_csr_kernel<<<(N_NODES * 64) / 256, 256, 0, stream>>>(rs, ep, g1, g2);

        gemm_out_kernel<<<1024, 256, 0, stream>>>(g2, W12, out);
    } else {
        hipMemsetAsync(g1, 0, (size_t)N_NODES * 32 * 2 * sizeof(float), stream);
        spmm32_atomic_kernel<<<(N_EDGES * 32) / 256, 256, 0, stream>>>(erow, ecol, eval_, feat, g1);
        spmm32_atomic_kernel<<<(N_EDGES * 32) / 256, 256, 0, stream>>>(erow, ecol, eval_, g1, g2);
        gemm_out_fallback_kernel<<<(N_NODES * 128) / 256, 256, 0, stream>>>(g2, W12, out);
    }
}